// Round 5
// baseline (244.115 us; speedup 1.0000x reference)
//
#include <hip/hip_runtime.h>

// STGraphConstructor: adj[b] = tanh(relu(A_b A_b^T) + I), A_b = [5096 x 64] fp32.
// R5: band-streaming geometry to fix DRAM write-page locality.
//  - R3 (coalesced-inst stores) == R4 (scattered-inst stores) == 140 us proved the
//    per-instruction store pattern is irrelevant; the macro address order of the
//    128x128 tile grid is the write-BW cap (~3.3 TB/s vs fill's 6.5 linear).
//  - Block = 64 rows x 640 cols; wave = 16-row strip sweeping 40 col-tiles.
//    K=64 lives in registers (A-frag loaded once); B-frags streamed, 4x L1 reuse.
//    XCD-pinned decode => each XCD writes a dense multi-band sweeping front.
//  - prep kernel (fp32 -> hi/lo bf16 panels) + 3-product MFMA unchanged (validated).

#define NSP 5000
#define NTM 96
#define MM  5096
#define DD  64
#define BR  64     // rows per block (4 waves x 16)
#define CC  640    // cols per block chunk
#define NBAND 80   // ceil(5096/64)
#define NCHUNK 8   // 8*640 = 5120 >= 5096
#define NTPW 40    // col-tiles per wave (CC/16)

typedef __attribute__((ext_vector_type(8))) short short8;
typedef __attribute__((ext_vector_type(8))) unsigned short ushort8;
typedef __attribute__((ext_vector_type(4))) float f32x4;

__device__ __forceinline__ unsigned short bf16_rn(float x) {
  unsigned u = __float_as_uint(x);
  u += 0x7FFFu + ((u >> 16) & 1u);
  return (unsigned short)(u >> 16);
}
__device__ __forceinline__ float bf16_f32(unsigned short s) {
  return __uint_as_float(((unsigned)s) << 16);
}

// ---- prep: convert concat(sp,tm) [B][MM][DD] fp32 -> hi/lo bf16 panels ----
__global__ __launch_bounds__(256) void stg_prep_kernel(
    const float* __restrict__ sp, const float* __restrict__ tm,
    unsigned short* __restrict__ wsh, unsigned short* __restrict__ wsl) {
  const int tid = blockIdx.x * 256 + threadIdx.x;
  const int flat = tid * 8;
  const int b = flat / (MM * DD);
  const int rem = flat - b * (MM * DD);
  const int m = rem / DD;
  const int d = rem - m * DD;
  const float* src = (m < NSP)
      ? sp + ((size_t)b * NSP + m) * DD + d
      : tm + ((size_t)b * NTM + (m - NSP)) * DD + d;
  const float4* s4 = reinterpret_cast<const float4*>(src);
  float f[8];
  {
    float4 v0 = s4[0], v1 = s4[1];
    f[0]=v0.x; f[1]=v0.y; f[2]=v0.z; f[3]=v0.w;
    f[4]=v1.x; f[5]=v1.y; f[6]=v1.z; f[7]=v1.w;
  }
  ushort8 H, L;
  #pragma unroll
  for (int i = 0; i < 8; ++i) {
    const unsigned short hi = bf16_rn(f[i]);
    H[i] = hi;
    L[i] = bf16_rn(f[i] - bf16_f32(hi));
  }
  *reinterpret_cast<ushort8*>(wsh + flat) = H;
  *reinterpret_cast<ushort8*>(wsl + flat) = L;
}

// ---- main: 64x640 block, wave = 16-row strip streaming 40 col-tiles ----
__global__ __launch_bounds__(256) void stg_adj_kernel(
    const unsigned short* __restrict__ wsh,
    const unsigned short* __restrict__ wsl,
    float* __restrict__ out) {
  // XCD pinning: x = wid%8 -> XCD; batch b owns residues {2b, 2b+1}.
  // Within a batch: tt enumerates (band, chunk) with chunk fastest, so the two
  // XCDs of a pair interleave chunks of the SAME band => dense write front.
  const int wid = blockIdx.x;
  const int x = wid & 7;
  const int b = x >> 1;
  const int tt = (wid >> 3) * 2 + (x & 1);   // 0..639
  const int band = tt >> 3;                  // 0..79
  const int chunk = tt & 7;                  // 0..7

  const int t = threadIdx.x;
  const int lane = t & 63;
  const int wave = t >> 6;
  const int lr = lane & 15;
  const int lg = lane >> 4;

  const size_t pb = (size_t)b * MM * DD;
  const char* Xh = reinterpret_cast<const char*>(wsh + pb);
  const char* Xl = reinterpret_cast<const char*>(wsl + pb);

  // A-frag (row side): 16 rows, K=64 in regs, loaded once.
  const int r0 = band * BR + wave * 16;
  const int gr = r0 + lr;                    // this lane's output row
  {
  }
  const int rowa = gr < MM ? gr : MM - 1;
  const unsigned offa = (unsigned)rowa * 128u + (unsigned)lg * 16u;
  const short8 ah0 = *reinterpret_cast<const short8*>(Xh + offa);
  const short8 ah1 = *reinterpret_cast<const short8*>(Xh + offa + 64u);
  const short8 al0 = *reinterpret_cast<const short8*>(Xl + offa);
  const short8 al1 = *reinterpret_cast<const short8*>(Xl + offa + 64u);

  const size_t cbase = (size_t)b * MM * MM;
  float* rowp = out + cbase + (size_t)gr * MM;   // valid only if gr < MM
  const int c0 = chunk * CC;
  const bool rok = gr < MM;

  #pragma unroll 4
  for (int ct = 0; ct < NTPW; ++ct) {
    const int gc0 = c0 + ct * 16;
    const int rowb = (gc0 + lr) < MM ? (gc0 + lr) : MM - 1;
    const unsigned offb = (unsigned)rowb * 128u + (unsigned)lg * 16u;
    const short8 bh0 = *reinterpret_cast<const short8*>(Xh + offb);
    const short8 bh1 = *reinterpret_cast<const short8*>(Xh + offb + 64u);
    const short8 bl0 = *reinterpret_cast<const short8*>(Xl + offb);
    const short8 bl1 = *reinterpret_cast<const short8*>(Xl + offb + 64u);

    f32x4 acc = (f32x4){0.f, 0.f, 0.f, 0.f};
    acc = __builtin_amdgcn_mfma_f32_16x16x32_bf16(bh0, ah0, acc, 0, 0, 0);
    acc = __builtin_amdgcn_mfma_f32_16x16x32_bf16(bh1, ah1, acc, 0, 0, 0);
    acc = __builtin_amdgcn_mfma_f32_16x16x32_bf16(bh0, al0, acc, 0, 0, 0);
    acc = __builtin_amdgcn_mfma_f32_16x16x32_bf16(bh1, al1, acc, 0, 0, 0);
    acc = __builtin_amdgcn_mfma_f32_16x16x32_bf16(bl0, ah0, acc, 0, 0, 0);
    acc = __builtin_amdgcn_mfma_f32_16x16x32_bf16(bl1, ah1, acc, 0, 0, 0);

    // lane holds row gr, cols gc0 + lg*4 + q  -> one float4 store
    const int gc = gc0 + lg * 4;
    if (rok && gc < MM) {
      f32x4 v;
      #pragma unroll
      for (int q = 0; q < 4; ++q) {
        float xv = fmaxf(acc[q], 0.f);
        xv += (gr == gc + q) ? 1.f : 0.f;
        const float e = __builtin_amdgcn_exp2f(xv * 2.8853900817779268f);
        v[q] = 1.f - 2.f * __builtin_amdgcn_rcpf(e + 1.f);
      }
      *reinterpret_cast<f32x4*>(rowp + gc) = v;
    }
  }
}

extern "C" void kernel_launch(void* const* d_in, const int* in_sizes, int n_in,
                              void* d_out, int out_size, void* d_ws, size_t ws_size,
                              hipStream_t stream) {
  const float* sp = (const float*)d_in[0];
  const float* tm = (const float*)d_in[1];
  float* out = (float*)d_out;
  const int B = in_sizes[0] / (NSP * DD);   // = 4
  unsigned short* wsh = (unsigned short*)d_ws;
  unsigned short* wsl = wsh + (size_t)B * MM * DD;

  const int prep_threads = B * MM * DD / 8;
  stg_prep_kernel<<<dim3(prep_threads / 256), dim3(256), 0, stream>>>(sp, tm, wsh, wsl);

  stg_adj_kernel<<<dim3(B * NBAND * NCHUNK), dim3(256), 0, stream>>>(wsh, wsl, out);
}

// Round 6
// 154.271 us; speedup vs baseline: 1.5824x; 1.5824x over previous
//
#include <hip/hip_runtime.h>

// STGraphConstructor: adj[b] = tanh(relu(A_b A_b^T) + I), A_b = [5096 x 64] fp32.
// R6: time-compact burst writes with 2KB-contiguous per-row runs.
//  - R5 lesson: instantaneous write stream is what matters. Dribbled 64B row-cursors
//    => 2.1 TB/s + 1.32x write amplification (half-dirty L2 evictions). Burst tile
//    epilogues (R1/R3/R4) => ~3.3 TB/s. Fill (linear) => 6.5 TB/s.
//  - Block = 32 rows x 512 cols ALL in registers (acc 64 VGPR). 4 waves share the
//    32 rows, split cols 128 each. Epilogue bursts 64KB: per row, the 4 waves tile
//    2KB contiguous (4x R4's run length). No LDS, no barriers, short-lived blocks.
//  - XCD-pinned: batch b -> XCD pair {2b,2b+1}; chunk-fastest band sweep.
//  - prep kernel (fp32 -> hi/lo bf16) + 3-product split-bf16 MFMA unchanged.

#define NSP 5000
#define NTM 96
#define MM  5096
#define DD  64
#define BR  32     // rows per block
#define CC  512    // cols per block
#define NB  160    // ceil(5096/32)
#define NCH 10     // 10*512 = 5120 >= 5096

typedef __attribute__((ext_vector_type(8))) short short8;
typedef __attribute__((ext_vector_type(8))) unsigned short ushort8;
typedef __attribute__((ext_vector_type(4))) float f32x4;

__device__ __forceinline__ unsigned short bf16_rn(float x) {
  unsigned u = __float_as_uint(x);
  u += 0x7FFFu + ((u >> 16) & 1u);
  return (unsigned short)(u >> 16);
}
__device__ __forceinline__ float bf16_f32(unsigned short s) {
  return __uint_as_float(((unsigned)s) << 16);
}

// ---- prep: convert concat(sp,tm) [B][MM][DD] fp32 -> hi/lo bf16 panels ----
__global__ __launch_bounds__(256) void stg_prep_kernel(
    const float* __restrict__ sp, const float* __restrict__ tm,
    unsigned short* __restrict__ wsh, unsigned short* __restrict__ wsl) {
  const int tid = blockIdx.x * 256 + threadIdx.x;
  const int flat = tid * 8;
  const int b = flat / (MM * DD);
  const int rem = flat - b * (MM * DD);
  const int m = rem / DD;
  const int d = rem - m * DD;
  const float* src = (m < NSP)
      ? sp + ((size_t)b * NSP + m) * DD + d
      : tm + ((size_t)b * NTM + (m - NSP)) * DD + d;
  const float4* s4 = reinterpret_cast<const float4*>(src);
  float f[8];
  {
    float4 v0 = s4[0], v1 = s4[1];
    f[0]=v0.x; f[1]=v0.y; f[2]=v0.z; f[3]=v0.w;
    f[4]=v1.x; f[5]=v1.y; f[6]=v1.z; f[7]=v1.w;
  }
  ushort8 H, L;
  #pragma unroll
  for (int i = 0; i < 8; ++i) {
    const unsigned short hi = bf16_rn(f[i]);
    H[i] = hi;
    L[i] = bf16_rn(f[i] - bf16_f32(hi));
  }
  *reinterpret_cast<ushort8*>(wsh + flat) = H;
  *reinterpret_cast<ushort8*>(wsl + flat) = L;
}

// ---- main: 32x512 register tile, burst epilogue ----
__global__ __launch_bounds__(256) void stg_adj_kernel(
    const unsigned short* __restrict__ wsh,
    const unsigned short* __restrict__ wsl,
    float* __restrict__ out) {
  // XCD pinning: x = wid%8 -> XCD; batch b owns residues {2b,2b+1}.
  // tt: chunk fastest => XCD pair interleaves chunks of the same band.
  const int wid = blockIdx.x;
  const int x = wid & 7;
  const int b = x >> 1;
  const int tt = (wid >> 3) * 2 + (x & 1);   // 0..1599
  const int band = tt / NCH;                 // 0..159
  const int chunk = tt - band * NCH;         // 0..9

  const int t = threadIdx.x;
  const int lane = t & 63;
  const int wave = t >> 6;
  const int lr = lane & 15;
  const int lg = lane >> 4;

  const size_t pb = (size_t)b * MM * DD;
  const char* Xh = reinterpret_cast<const char*>(wsh + pb);
  const char* Xl = reinterpret_cast<const char*>(wsl + pb);

  const int r0 = band * BR;                  // block's 32 rows
  const int c0w = chunk * CC + wave * 128;   // this wave's 128-col strip

  // A-frags for both 16-row groups, K=64 in regs (verified R4 operand scheme)
  short8 ah[2][2], al[2][2];
  #pragma unroll
  for (int rg = 0; rg < 2; ++rg) {
    int rr = r0 + rg * 16 + lr; rr = rr < MM ? rr : MM - 1;
    const unsigned offa = (unsigned)rr * 128u + (unsigned)lg * 16u;
    ah[rg][0] = *reinterpret_cast<const short8*>(Xh + offa);
    ah[rg][1] = *reinterpret_cast<const short8*>(Xh + offa + 64u);
    al[rg][0] = *reinterpret_cast<const short8*>(Xl + offa);
    al[rg][1] = *reinterpret_cast<const short8*>(Xl + offa + 64u);
  }

  f32x4 acc[2][8];
  #pragma unroll
  for (int rg = 0; rg < 2; ++rg)
    #pragma unroll
    for (int ct = 0; ct < 8; ++ct)
      acc[rg][ct] = (f32x4){0.f, 0.f, 0.f, 0.f};

  #pragma unroll
  for (int ct = 0; ct < 8; ++ct) {
    const int gc0 = c0w + ct * 16;
    int rb = gc0 + lr; rb = rb < MM ? rb : MM - 1;
    const unsigned offb = (unsigned)rb * 128u + (unsigned)lg * 16u;
    const short8 bh0 = *reinterpret_cast<const short8*>(Xh + offb);
    const short8 bh1 = *reinterpret_cast<const short8*>(Xh + offb + 64u);
    const short8 bl0 = *reinterpret_cast<const short8*>(Xl + offb);
    const short8 bl1 = *reinterpret_cast<const short8*>(Xl + offb + 64u);
    #pragma unroll
    for (int rg = 0; rg < 2; ++rg) {
      acc[rg][ct] = __builtin_amdgcn_mfma_f32_16x16x32_bf16(bh0, ah[rg][0], acc[rg][ct], 0, 0, 0);
      acc[rg][ct] = __builtin_amdgcn_mfma_f32_16x16x32_bf16(bh1, ah[rg][1], acc[rg][ct], 0, 0, 0);
      acc[rg][ct] = __builtin_amdgcn_mfma_f32_16x16x32_bf16(bh0, al[rg][0], acc[rg][ct], 0, 0, 0);
      acc[rg][ct] = __builtin_amdgcn_mfma_f32_16x16x32_bf16(bh1, al[rg][1], acc[rg][ct], 0, 0, 0);
      acc[rg][ct] = __builtin_amdgcn_mfma_f32_16x16x32_bf16(bl0, ah[rg][0], acc[rg][ct], 0, 0, 0);
      acc[rg][ct] = __builtin_amdgcn_mfma_f32_16x16x32_bf16(bl1, ah[rg][1], acc[rg][ct], 0, 0, 0);
    }
  }

  // ---- burst epilogue: tanh(relu(x)+eye); 4 waves tile 2KB contiguous per row ----
  const size_t cbase = (size_t)b * MM * MM;
  #pragma unroll
  for (int rg = 0; rg < 2; ++rg) {
    const int gr = r0 + rg * 16 + lr;
    if (gr < MM) {
      float* rowp = out + cbase + (size_t)gr * MM;
      #pragma unroll
      for (int ct = 0; ct < 8; ++ct) {
        const int gc = c0w + ct * 16 + lg * 4;
        if (gc < MM) {   // gc,MM multiples of 4 => whole float4 in bounds
          f32x4 v;
          #pragma unroll
          for (int q = 0; q < 4; ++q) {
            float xv = fmaxf(acc[rg][ct][q], 0.f);
            xv += (gr == gc + q) ? 1.f : 0.f;
            const float e = __builtin_amdgcn_exp2f(xv * 2.8853900817779268f);
            v[q] = 1.f - 2.f * __builtin_amdgcn_rcpf(e + 1.f);
          }
          *reinterpret_cast<f32x4*>(rowp + gc) = v;
        }
      }
    }
  }
}

extern "C" void kernel_launch(void* const* d_in, const int* in_sizes, int n_in,
                              void* d_out, int out_size, void* d_ws, size_t ws_size,
                              hipStream_t stream) {
  const float* sp = (const float*)d_in[0];
  const float* tm = (const float*)d_in[1];
  float* out = (float*)d_out;
  const int B = in_sizes[0] / (NSP * DD);   // = 4
  unsigned short* wsh = (unsigned short*)d_ws;
  unsigned short* wsl = wsh + (size_t)B * MM * DD;

  const int prep_threads = B * MM * DD / 8;
  stg_prep_kernel<<<dim3(prep_threads / 256), dim3(256), 0, stream>>>(sp, tm, wsh, wsl);

  stg_adj_kernel<<<dim3(B * NB * NCH), dim3(256), 0, stream>>>(wsh, wsl, out);
}